// Round 4
// baseline (185.816 us; speedup 1.0000x reference)
//
#include <hip/hip_runtime.h>
#include <math.h>

// Problem constants: N=8, S=8192, C=1, K=1024, V=64
#define NS   65536
#define KK   1024
#define VV   64
#define SPB  128              // samples per block (4 waves x 32)
#define NB   512              // grid = NS/SPB
#define NCH  8                // chunks of 128 codes
#define CHC  128              // codes per chunk
#define ROWB 144              // padded LDS row bytes (128 data + 16 pad -> 2-way max bank alias)

// Output layout (flat, return order):
#define OUT0_OFF 0            // (8,8192,1,64) = 4,194,304
#define OUT1_OFF 4194304
#define OUT2_OFF 4259840
#define ENT_OFF  4325376      // entropy scalar; doubles as completion counter

// ws layout: [0,4K) hist u32; [4K,8K) enorm f32; [8K,8K+128K) bf16 codebook [1024][64]

typedef __attribute__((ext_vector_type(8))) short bf16x8;
typedef __attribute__((ext_vector_type(4))) float f32x4;

__device__ __forceinline__ short f2bf(float f) {
    unsigned u = __float_as_uint(f);
    u = (u + 0x7fffu + ((u >> 16) & 1u)) >> 16;   // RNE
    return (short)u;
}

__global__ void vq_prep(const float* __restrict__ emb, unsigned int* __restrict__ hist,
                        float* __restrict__ enorm, short* __restrict__ cb,
                        unsigned int* __restrict__ entCnt) {
    int t = blockIdx.x * blockDim.x + threadIdx.x;   // 0..1023
    if (t == 0) entCnt[0] = 0u;
    if (t < KK) {
        hist[t] = 0u;
        const float4* e4 = (const float4*)(emb + (size_t)t * VV);
        float s = 0.f;
        union { short sh[8]; bf16x8 v; } pk;
        bf16x8* dst = (bf16x8*)(cb + (size_t)t * VV);
        #pragma unroll
        for (int i = 0; i < 8; ++i) {
            float4 f0 = e4[2 * i], f1 = e4[2 * i + 1];
            s = fmaf(f0.x, f0.x, s); s = fmaf(f0.y, f0.y, s);
            s = fmaf(f0.z, f0.z, s); s = fmaf(f0.w, f0.w, s);
            s = fmaf(f1.x, f1.x, s); s = fmaf(f1.y, f1.y, s);
            s = fmaf(f1.z, f1.z, s); s = fmaf(f1.w, f1.w, s);
            pk.sh[0] = f2bf(f0.x); pk.sh[1] = f2bf(f0.y);
            pk.sh[2] = f2bf(f0.z); pk.sh[3] = f2bf(f0.w);
            pk.sh[4] = f2bf(f1.x); pk.sh[5] = f2bf(f1.y);
            pk.sh[6] = f2bf(f1.z); pk.sh[7] = f2bf(f1.w);
            dst[i] = pk.v;
        }
        enorm[t] = s;
    }
}

__global__ __launch_bounds__(256, 2) void vq_main(
    const float* __restrict__ x, const float* __restrict__ emb,
    const float* __restrict__ enorm, const short* __restrict__ cb,
    unsigned int* __restrict__ hist,
    float* __restrict__ out0, float* __restrict__ out1, float* __restrict__ out2,
    float* __restrict__ entOut)
{
    __shared__ __align__(16) char  sCB[2][CHC * ROWB];   // 2 x 18 KB, padded rows
    __shared__ __align__(16) float sEN[2][CHC];
    __shared__ int   sBest[SPB];
    __shared__ float sPart[4];
    __shared__ unsigned sLast;

    const int tid  = threadIdx.x;
    const int wv   = tid >> 6;
    const int lane = tid & 63;
    const int col  = lane & 15;
    const int quad = lane >> 4;
    const int sampBlk  = blockIdx.x * SPB;
    const int sampWave = sampBlk + wv * 32;

    // ---- A fragments for 2 sample-tiles (32 samples/wave), verified 16x16x32 layout ----
    bf16x8 a0, a1, a2, a3;
    {
        const float* xp = x + (size_t)(sampWave + col) * VV + quad * 8;
        float4 p0 = *(const float4*)(xp);
        float4 p1 = *(const float4*)(xp + 4);
        float4 p2 = *(const float4*)(xp + 32);
        float4 p3 = *(const float4*)(xp + 36);
        const float* xq = xp + 16 * VV;
        float4 q0 = *(const float4*)(xq);
        float4 q1 = *(const float4*)(xq + 4);
        float4 q2 = *(const float4*)(xq + 32);
        float4 q3 = *(const float4*)(xq + 36);
        a0[0]=f2bf(p0.x); a0[1]=f2bf(p0.y); a0[2]=f2bf(p0.z); a0[3]=f2bf(p0.w);
        a0[4]=f2bf(p1.x); a0[5]=f2bf(p1.y); a0[6]=f2bf(p1.z); a0[7]=f2bf(p1.w);
        a1[0]=f2bf(p2.x); a1[1]=f2bf(p2.y); a1[2]=f2bf(p2.z); a1[3]=f2bf(p2.w);
        a1[4]=f2bf(p3.x); a1[5]=f2bf(p3.y); a1[6]=f2bf(p3.z); a1[7]=f2bf(p3.w);
        a2[0]=f2bf(q0.x); a2[1]=f2bf(q0.y); a2[2]=f2bf(q0.z); a2[3]=f2bf(q0.w);
        a2[4]=f2bf(q1.x); a2[5]=f2bf(q1.y); a2[6]=f2bf(q1.z); a2[7]=f2bf(q1.w);
        a3[0]=f2bf(q2.x); a3[1]=f2bf(q2.y); a3[2]=f2bf(q2.z); a3[3]=f2bf(q2.w);
        a3[4]=f2bf(q3.x); a3[5]=f2bf(q3.y); a3[6]=f2bf(q3.z); a3[7]=f2bf(q3.w);
    }

    // ---- stage chunk 0 ----
    {
        const float4* g = (const float4*)(cb);        // 16B granules: code=gid>>3, g=gid&7
        #pragma unroll
        for (int i = 0; i < 4; ++i) {
            int gid = i * 256 + tid;
            float4 v = g[gid];
            *(float4*)(sCB[0] + (gid >> 3) * ROWB + (gid & 7) * 16) = v;
        }
        if (tid < 32) ((float4*)sEN[0])[tid] = ((const float4*)enorm)[tid];
    }
    __syncthreads();

    float bs[8];
    int   bt[8];
    #pragma unroll
    for (int r = 0; r < 8; ++r) { bs[r] = INFINITY; bt[r] = 0; }

    const int m7 = col & 7;
    const int laneRowOff = col * ROWB + ((quad ^ m7) << 4);  // swizzle-free pad layout: quad granule
    // NOTE: with pad-144 no swizzle needed; granule pos = quad. Recompute simple offset:
    const int b0lane = col * ROWB + quad * 16;

    for (int ch = 0; ch < NCH; ++ch) {
        const int b = ch & 1;
        // prefetch next chunk into registers
        float4 pf0, pf1, pf2, pf3, pfe;
        const bool has = (ch + 1) < NCH;
        if (has) {
            const float4* g = (const float4*)(cb + (size_t)(ch + 1) * CHC * VV);
            pf0 = g[0 * 256 + tid];
            pf1 = g[1 * 256 + tid];
            pf2 = g[2 * 256 + tid];
            pf3 = g[3 * 256 + tid];
            if (tid < 32) pfe = ((const float4*)(enorm + (ch + 1) * CHC))[tid];
        }

        const char*  cbB = sCB[b];
        const float* enB = sEN[b];
        #pragma unroll
        for (int t2 = 0; t2 < 8; ++t2) {
            bf16x8 b0 = *(const bf16x8*)(cbB + t2 * 16 * ROWB + b0lane);
            bf16x8 b1 = *(const bf16x8*)(cbB + t2 * 16 * ROWB + b0lane + 64);
            float enk = enB[t2 * 16 + col];
            f32x4 z = {0.f, 0.f, 0.f, 0.f};
            f32x4 A0 = __builtin_amdgcn_mfma_f32_16x16x32_bf16(a1, b1, z, 0, 0, 0);
            A0       = __builtin_amdgcn_mfma_f32_16x16x32_bf16(a0, b0, A0, 0, 0, 0);
            f32x4 A1 = __builtin_amdgcn_mfma_f32_16x16x32_bf16(a3, b1, z, 0, 0, 0);
            A1       = __builtin_amdgcn_mfma_f32_16x16x32_bf16(a2, b0, A1, 0, 0, 0);
            const int ccode = (ch * 8 + t2) * 16 + col;
            #pragma unroll
            for (int r = 0; r < 4; ++r) {
                float sc0 = fmaf(-2.f, A0[r], enk);
                bool c0 = sc0 < bs[r];
                bs[r] = c0 ? sc0 : bs[r];
                bt[r] = c0 ? ccode : bt[r];
                float sc1 = fmaf(-2.f, A1[r], enk);
                bool c1 = sc1 < bs[4 + r];
                bs[4 + r] = c1 ? sc1 : bs[4 + r];
                bt[4 + r] = c1 ? ccode : bt[4 + r];
            }
        }

        if (has) {
            char* dst = sCB[b ^ 1];
            *(float4*)(dst + ((0*256+tid) >> 3) * ROWB + ((0*256+tid) & 7) * 16) = pf0;
            *(float4*)(dst + ((1*256+tid) >> 3) * ROWB + ((1*256+tid) & 7) * 16) = pf1;
            *(float4*)(dst + ((2*256+tid) >> 3) * ROWB + ((2*256+tid) & 7) * 16) = pf2;
            *(float4*)(dst + ((3*256+tid) >> 3) * ROWB + ((3*256+tid) & 7) * 16) = pf3;
            if (tid < 32) ((float4*)sEN[b ^ 1])[tid] = pfe;
        }
        __syncthreads();
    }

    // ---- reduce best over the 16 col-lanes of each quad group ----
    #pragma unroll
    for (int off = 1; off < 16; off <<= 1) {
        #pragma unroll
        for (int r = 0; r < 8; ++r) {
            float os = __shfl_xor(bs[r], off, 64);
            int   oc = __shfl_xor(bt[r], off, 64);
            bool take = (os < bs[r]) || (os == bs[r] && oc < bt[r]);
            bs[r] = take ? os : bs[r];
            bt[r] = take ? oc : bt[r];
        }
    }
    if (col == 0) {
        #pragma unroll
        for (int r = 0; r < 4; ++r) {
            sBest[wv * 32 + quad * 4 + r]      = bt[r];      // D row = quad*4+r (tile 0)
            sBest[wv * 32 + 16 + quad * 4 + r] = bt[4 + r];  // tile 1
        }
    }
    __syncthreads();

    // ---- exact fp32 d^2 epilogue (one thread per sample) ----
    if (tid < SPB) {
        const int n = sampBlk + tid;
        const int best = sBest[tid];
        const float4* xp = (const float4*)(x   + (size_t)n    * VV);
        const float4* ep = (const float4*)(emb + (size_t)best * VV);
        float d = 0.f;
        #pragma unroll
        for (int i = 0; i < 16; ++i) {
            float4 xv = xp[i], ev = ep[i];
            float t0 = xv.x - ev.x, t1 = xv.y - ev.y, t2 = xv.z - ev.z, t3 = xv.w - ev.w;
            d = fmaf(t0, t0, d); d = fmaf(t1, t1, d);
            d = fmaf(t2, t2, d); d = fmaf(t3, t3, d);
        }
        out1[n] = d;
        out2[n] = d;
        atomicAdd(&hist[best], 1u);
    }

    // ---- coalesced out0 gather-write (exact fp32 emb) ----
    {
        const int smp = tid >> 1;                 // 128 samples x 2 halves
        const int half = tid & 1;
        const int best = sBest[smp];
        const float4* ep = (const float4*)(emb + (size_t)best * VV + half * 32);
        float4* op = (float4*)(out0 + (size_t)(sampBlk + smp) * VV + half * 32);
        #pragma unroll
        for (int i = 0; i < 8; ++i) op[i] = ep[i];
    }

    // ---- completion counter + fused entropy in the last block ----
    __threadfence();
    __syncthreads();
    unsigned int* entCnt = (unsigned int*)entOut;
    if (tid == 0) {
        unsigned old = atomicAdd(entCnt, 1u);
        sLast = (old == (NB - 1)) ? 1u : 0u;
    }
    __syncthreads();
    if (sLast) {
        float e = 0.f;
        #pragma unroll
        for (int i = 0; i < 4; ++i) {
            unsigned c = atomicAdd(&hist[tid * 4 + i], 0u);   // coherent read
            if (c) { float p = (float)c * (1.0f / (float)NS); e -= p * logf(p); }
        }
        #pragma unroll
        for (int off = 32; off > 0; off >>= 1) e += __shfl_down(e, off, 64);
        if (lane == 0) sPart[wv] = e;
        __syncthreads();
        if (tid == 0) entOut[0] = sPart[0] + sPart[1] + sPart[2] + sPart[3];
    }
}

extern "C" void kernel_launch(void* const* d_in, const int* in_sizes, int n_in,
                              void* d_out, int out_size, void* d_ws, size_t ws_size,
                              hipStream_t stream) {
    const float* x   = (const float*)d_in[0];   // (8,8192,1,64) fp32
    const float* emb = (const float*)d_in[1];   // (1,1024,64) fp32
    float* out = (float*)d_out;
    unsigned int* hist  = (unsigned int*)d_ws;
    float*        enorm = (float*)((char*)d_ws + 4096);
    short*        cb    = (short*)((char*)d_ws + 8192);   // bf16 codebook, 128 KB

    vq_prep<<<4, 256, 0, stream>>>(emb, hist, enorm, cb, (unsigned int*)(out + ENT_OFF));
    vq_main<<<NB, 256, 0, stream>>>(x, emb, enorm, cb, hist,
                                    out + OUT0_OFF, out + OUT1_OFF, out + OUT2_OFF,
                                    out + ENT_OFF);
}

// Round 5
// 139.535 us; speedup vs baseline: 1.3317x; 1.3317x over previous
//
#include <hip/hip_runtime.h>
#include <math.h>

// Problem constants: N=8, S=8192, C=1, K=1024, V=64
#define NS   65536
#define KK   1024
#define VV   64
#define NT   64               // 64 code-tiles of 16
#define SPW  32               // samples per wave (= per block; 1-wave blocks)
#define NB   (NS / SPW)       // 2048 blocks

// Output layout (flat, return order):
#define OUT0_OFF 0            // (8,8192,1,64) = 4,194,304
#define OUT1_OFF 4194304
#define OUT2_OFF 4259840
#define ENT_OFF  4325376      // entropy scalar; doubles as completion counter

// ws layout: [0,4K) hist u32; [4K,8K) enorm f32; [8K,8K+128K) bf16 codebook [1024][64]

typedef __attribute__((ext_vector_type(8))) short bf16x8;
typedef __attribute__((ext_vector_type(4))) float f32x4;

__device__ __forceinline__ short f2bf(float f) {
    unsigned u = __float_as_uint(f);
    u = (u + 0x7fffu + ((u >> 16) & 1u)) >> 16;   // RNE
    return (short)u;
}

__global__ void vq_prep(const float* __restrict__ emb, unsigned int* __restrict__ hist,
                        float* __restrict__ enorm, short* __restrict__ cb,
                        unsigned int* __restrict__ entCnt) {
    int t = blockIdx.x * blockDim.x + threadIdx.x;   // 0..1023 (one code per thread)
    if (t == 0) entCnt[0] = 0u;
    if (t < KK) {
        hist[t] = 0u;
        const float4* e4 = (const float4*)(emb + (size_t)t * VV);
        float s = 0.f;
        union { short sh[8]; bf16x8 v; } pk;
        bf16x8* dst = (bf16x8*)(cb + (size_t)t * VV);
        #pragma unroll
        for (int i = 0; i < 8; ++i) {
            float4 f0 = e4[2 * i], f1 = e4[2 * i + 1];
            s = fmaf(f0.x, f0.x, s); s = fmaf(f0.y, f0.y, s);
            s = fmaf(f0.z, f0.z, s); s = fmaf(f0.w, f0.w, s);
            s = fmaf(f1.x, f1.x, s); s = fmaf(f1.y, f1.y, s);
            s = fmaf(f1.z, f1.z, s); s = fmaf(f1.w, f1.w, s);
            pk.sh[0] = f2bf(f0.x); pk.sh[1] = f2bf(f0.y);
            pk.sh[2] = f2bf(f0.z); pk.sh[3] = f2bf(f0.w);
            pk.sh[4] = f2bf(f1.x); pk.sh[5] = f2bf(f1.y);
            pk.sh[6] = f2bf(f1.z); pk.sh[7] = f2bf(f1.w);
            dst[i] = pk.v;
        }
        enorm[t] = s;
    }
}

// argmin(|e|^2 - 2 x.e)  ==  argmax(x.e - 0.5|e|^2): fold -0.5|e|^2 into the
// MFMA C-init so the selection needs no per-score fma.
#define TILE_COMPUTE(T, B0, B1, EN) do {                                        \
    const float cinit_ = -0.5f * (EN);                                          \
    f32x4 acc0_ = {cinit_, cinit_, cinit_, cinit_};                             \
    f32x4 acc1_ = acc0_;                                                        \
    acc0_ = __builtin_amdgcn_mfma_f32_16x16x32_bf16(a0, (B0), acc0_, 0, 0, 0);  \
    acc0_ = __builtin_amdgcn_mfma_f32_16x16x32_bf16(a1, (B1), acc0_, 0, 0, 0);  \
    acc1_ = __builtin_amdgcn_mfma_f32_16x16x32_bf16(a2, (B0), acc1_, 0, 0, 0);  \
    acc1_ = __builtin_amdgcn_mfma_f32_16x16x32_bf16(a3, (B1), acc1_, 0, 0, 0);  \
    const int ccode_ = (T) * 16 + col;                                          \
    _Pragma("unroll")                                                           \
    for (int r_ = 0; r_ < 4; ++r_) {                                            \
        bool g0_ = acc0_[r_] > bs[r_];                                          \
        bs[r_] = g0_ ? acc0_[r_] : bs[r_];                                      \
        bt[r_] = g0_ ? ccode_ : bt[r_];                                         \
        bool g1_ = acc1_[r_] > bs[4 + r_];                                      \
        bs[4 + r_] = g1_ ? acc1_[r_] : bs[4 + r_];                              \
        bt[4 + r_] = g1_ ? ccode_ : bt[4 + r_];                                 \
    }                                                                           \
} while (0)

__global__ __launch_bounds__(64, 4) void vq_main(
    const float* __restrict__ x, const float* __restrict__ emb,
    const float* __restrict__ enorm, const short* __restrict__ cb,
    unsigned int* __restrict__ hist,
    float* __restrict__ out0, float* __restrict__ out1, float* __restrict__ out2,
    float* __restrict__ entOut)
{
    __shared__ int sBest[SPW];
    __shared__ unsigned sLast;

    const int lane = threadIdx.x;     // one wave per block
    const int col  = lane & 15;       // code-within-tile / A row m
    const int quad = lane >> 4;       // k-group
    const int samp0 = blockIdx.x * SPW;

    // ---- A fragments for 2 sample-tiles (verified 16x16x32 layout) ----
    bf16x8 a0, a1, a2, a3;
    {
        const float* xp = x + (size_t)(samp0 + col) * VV + quad * 8;
        float4 p0 = *(const float4*)(xp);
        float4 p1 = *(const float4*)(xp + 4);
        float4 p2 = *(const float4*)(xp + 32);
        float4 p3 = *(const float4*)(xp + 36);
        const float* xq = xp + 16 * VV;
        float4 q0 = *(const float4*)(xq);
        float4 q1 = *(const float4*)(xq + 4);
        float4 q2 = *(const float4*)(xq + 32);
        float4 q3 = *(const float4*)(xq + 36);
        a0[0]=f2bf(p0.x); a0[1]=f2bf(p0.y); a0[2]=f2bf(p0.z); a0[3]=f2bf(p0.w);
        a0[4]=f2bf(p1.x); a0[5]=f2bf(p1.y); a0[6]=f2bf(p1.z); a0[7]=f2bf(p1.w);
        a1[0]=f2bf(p2.x); a1[1]=f2bf(p2.y); a1[2]=f2bf(p2.z); a1[3]=f2bf(p2.w);
        a1[4]=f2bf(p3.x); a1[5]=f2bf(p3.y); a1[6]=f2bf(p3.z); a1[7]=f2bf(p3.w);
        a2[0]=f2bf(q0.x); a2[1]=f2bf(q0.y); a2[2]=f2bf(q0.z); a2[3]=f2bf(q0.w);
        a2[4]=f2bf(q1.x); a2[5]=f2bf(q1.y); a2[6]=f2bf(q1.z); a2[7]=f2bf(q1.w);
        a3[0]=f2bf(q2.x); a3[1]=f2bf(q2.y); a3[2]=f2bf(q2.z); a3[3]=f2bf(q2.w);
        a3[4]=f2bf(q3.x); a3[5]=f2bf(q3.y); a3[6]=f2bf(q3.z); a3[7]=f2bf(q3.w);
    }

    float bs[8];
    int   bt[8];
    #pragma unroll
    for (int r = 0; r < 8; ++r) { bs[r] = -INFINITY; bt[r] = 0; }

    // ---- depth-2 pipelined stream over all 64 tiles (barrier-free, L2-fed) ----
    const short* bptr = cb + col * VV + quad * 8;   // tile t at +t*16*VV elements
    const float* ep   = enorm + col;

    bf16x8 c0 = *(const bf16x8*)(bptr);
    bf16x8 c1 = *(const bf16x8*)(bptr + 32);
    float  enC = ep[0];
    bf16x8 n0 = *(const bf16x8*)(bptr + 16 * VV);
    bf16x8 n1 = *(const bf16x8*)(bptr + 16 * VV + 32);
    float  enN = ep[16];

    #pragma unroll 2
    for (int t = 0; t < NT - 2; ++t) {
        const short* pp = bptr + (size_t)(t + 2) * (16 * VV);
        bf16x8 p0 = *(const bf16x8*)pp;
        bf16x8 p1 = *(const bf16x8*)(pp + 32);
        float  enP = ep[(t + 2) * 16];
        TILE_COMPUTE(t, c0, c1, enC);
        c0 = n0; c1 = n1; enC = enN;
        n0 = p0; n1 = p1; enN = enP;
    }
    TILE_COMPUTE(NT - 2, c0, c1, enC);
    TILE_COMPUTE(NT - 1, n0, n1, enN);

    // ---- reduce argmax over the 16 col-lanes of each quad group ----
    #pragma unroll
    for (int off = 1; off < 16; off <<= 1) {
        #pragma unroll
        for (int r = 0; r < 8; ++r) {
            float os = __shfl_xor(bs[r], off, 64);
            int   oc = __shfl_xor(bt[r], off, 64);
            bool take = (os > bs[r]) || (os == bs[r] && oc < bt[r]);
            bs[r] = take ? os : bs[r];
            bt[r] = take ? oc : bt[r];
        }
    }
    if (col == 0) {
        #pragma unroll
        for (int r = 0; r < 4; ++r) {
            sBest[quad * 4 + r]      = bt[r];       // D row = quad*4+r (tile 0)
            sBest[16 + quad * 4 + r] = bt[4 + r];   // tile 1
        }
    }
    __syncthreads();   // single-wave block: compiles to a cheap waitcnt

    // ---- exact fp32 d^2 epilogue (one lane per sample) ----
    if (lane < SPW) {
        const int n = samp0 + lane;
        const int best = sBest[lane];
        const float4* xp4 = (const float4*)(x   + (size_t)n    * VV);
        const float4* ep4 = (const float4*)(emb + (size_t)best * VV);
        float d = 0.f;
        #pragma unroll
        for (int i = 0; i < 16; ++i) {
            float4 xv = xp4[i], ev = ep4[i];
            float t0 = xv.x - ev.x, t1 = xv.y - ev.y, t2 = xv.z - ev.z, t3 = xv.w - ev.w;
            d = fmaf(t0, t0, d); d = fmaf(t1, t1, d);
            d = fmaf(t2, t2, d); d = fmaf(t3, t3, d);
        }
        out1[n] = d;
        out2[n] = d;
        atomicAdd(&hist[best], 1u);
    }

    // ---- coalesced out0 gather-write: lane covers a contiguous 128B half-row ----
    {
        const int smp  = lane >> 1;
        const int half = lane & 1;
        const int best = sBest[smp];
        const float4* src = (const float4*)(emb + (size_t)best * VV + half * 32);
        float4*       dst = (float4*)(out0 + (size_t)(samp0 + smp) * VV + half * 32);
        #pragma unroll
        for (int i = 0; i < 8; ++i) dst[i] = src[i];
    }

    // ---- completion counter + fused entropy in the last block ----
    // Drain this wave's hist atomics (vmcnt) before the counter add; atomics are
    // L2-home coherent, so no cache writeback (threadfence) is needed.
    __builtin_amdgcn_s_waitcnt(0);
    unsigned int* entCnt = (unsigned int*)entOut;
    if (lane == 0) sLast = (atomicAdd(entCnt, 1u) == (NB - 1)) ? 1u : 0u;
    __syncthreads();
    if (sLast) {
        float e = 0.f;
        #pragma unroll
        for (int i = 0; i < 16; ++i) {
            unsigned c = atomicAdd(&hist[i * 64 + lane], 0u);   // coherent read
            if (c) { float p = (float)c * (1.0f / (float)NS); e -= p * logf(p); }
        }
        #pragma unroll
        for (int off = 32; off > 0; off >>= 1) e += __shfl_down(e, off, 64);
        if (lane == 0) entOut[0] = e;
    }
}

extern "C" void kernel_launch(void* const* d_in, const int* in_sizes, int n_in,
                              void* d_out, int out_size, void* d_ws, size_t ws_size,
                              hipStream_t stream) {
    const float* x   = (const float*)d_in[0];   // (8,8192,1,64) fp32
    const float* emb = (const float*)d_in[1];   // (1,1024,64) fp32
    float* out = (float*)d_out;
    unsigned int* hist  = (unsigned int*)d_ws;
    float*        enorm = (float*)((char*)d_ws + 4096);
    short*        cb    = (short*)((char*)d_ws + 8192);   // bf16 codebook, 128 KB

    vq_prep<<<4, 256, 0, stream>>>(emb, hist, enorm, cb, (unsigned int*)(out + ENT_OFF));
    vq_main<<<NB, 64, 0, stream>>>(x, emb, enorm, cb, hist,
                                   out + OUT0_OFF, out + OUT1_OFF, out + OUT2_OFF,
                                   out + ENT_OFF);
}